// Round 2
// baseline (91.535 us; speedup 1.0000x reference)
//
#include <hip/hip_runtime.h>
#include <math.h>

// Batched histogram entropy: B rows x 64 int32 tokens, VOCAB=40.
// Round-2 design: one lane = one row. No LDS atomics-with-return, no
// shuffles, no per-element table lookups -> no DS latency chains.
//
//  1. Stage 64 rows (one per lane) via coalesced int4 loads, pack 4 vals
//     into bytes (v < 40), ds_write_b32 into a transposed tile
//     (row stride 80 B: 16B-aligned for b128 reads, bank-uniform).
//  2. Each lane reads its own packed row: 4 x ds_read_b128.
//  3. Per-lane byte-packed histogram (10 ints used, stride 12 ints = 48 B):
//     counting = fire-and-forget ds_add_u32 of 1<<(8*(v&3)). Counts <= 64
//     so no byte carry. No return values => no lgkm chains.
//  4. Sweep: 3 x ds_read_b128, unpack 40 bytes, 40 v_log_f32 on the VALU.
//     Coalesced 256 B output store per wave.

#define NVOCAB 40

constexpr int BLOCK = 256;
constexpr int WPB = 4;           // waves per block
constexpr int TSTRIDE = 20;      // ints per packed tile row (16 used + 4 pad)
constexpr int HSTRIDE = 12;      // ints per lane histogram (10 used + 2 pad)

__global__ __launch_bounds__(BLOCK) void entropy_rowlane_kernel(
    const int* __restrict__ x, float* __restrict__ out, int nbatch) {
  __shared__ int tile[WPB * 64 * TSTRIDE];   // 20480 B
  __shared__ int hist[WPB * 64 * HSTRIDE];   // 12288 B

  const int tid = threadIdx.x;
  const int l   = tid & 63;
  const int wv  = tid >> 6;

  int* const tbase = &tile[wv * 64 * TSTRIDE];
  int* const hbase = &hist[(wv * 64 + l) * HSTRIDE];

  // Zero my histogram (in-order DS: completes before any ds_add below).
  const int4 z = make_int4(0, 0, 0, 0);
  ((int4*)hbase)[0] = z;
  ((int4*)hbase)[1] = z;
  ((int4*)hbase)[2] = z;

  const int4* const x4 = (const int4*)x;

  int batch = blockIdx.x * WPB + wv;
  const int batch_step = gridDim.x * WPB;

  for (; batch < nbatch; batch += batch_step) {
    const long base4 = (long)batch * 1024;  // int4 index of this 64-row batch

    // ---- stage: 16 coalesced 1 KiB loads, all in flight ----
    int4 va[8], vb[8];
#pragma unroll
    for (int t = 0; t < 8; ++t) va[t] = x4[base4 + t * 64 + l];
#pragma unroll
    for (int t = 0; t < 8; ++t) vb[t] = x4[base4 + (t + 8) * 64 + l];

    const int wrow = l >> 4;   // which of the 4 rows this lane's chunk feeds
    const int wcol = l & 15;   // packed-int column within the row
#pragma unroll
    for (int t = 0; t < 8; ++t) {
      int p = va[t].x | (va[t].y << 8) | (va[t].z << 16) | (va[t].w << 24);
      tbase[(4 * t + wrow) * TSTRIDE + wcol] = p;
    }
#pragma unroll
    for (int t = 0; t < 8; ++t) {
      int p = vb[t].x | (vb[t].y << 8) | (vb[t].z << 16) | (vb[t].w << 24);
      tbase[(4 * (t + 8) + wrow) * TSTRIDE + wcol] = p;
    }

    // Cross-lane LDS RAW: HW DS ops are wave-in-order; this zero-cost
    // scheduling fence stops the compiler reordering reads above writes.
    __builtin_amdgcn_wave_barrier();

    // ---- my packed row: 64 B = 4 x ds_read_b128 ----
    const int4* const rbase = (const int4*)(tbase + l * TSTRIDE);
    int4 r0 = rbase[0], r1 = rbase[1], r2 = rbase[2], r3 = rbase[3];
    int rw[16] = {r0.x, r0.y, r0.z, r0.w, r1.x, r1.y, r1.z, r1.w,
                  r2.x, r2.y, r2.z, r2.w, r3.x, r3.y, r3.z, r3.w};

    // ---- count: 64 fire-and-forget ds_add_u32, byte-packed bins ----
#pragma unroll
    for (int i = 0; i < 16; ++i) {
      unsigned w = (unsigned)rw[i];
#pragma unroll
      for (int b = 0; b < 4; ++b) {
        unsigned v = (w >> (8 * b)) & 0xFFu;
        atomicAdd((unsigned*)&hbase[v >> 2], 1u << ((v << 3) & 24u));
      }
    }

    __builtin_amdgcn_wave_barrier();

    // ---- sweep: read 40 byte-counters, entropy on the VALU ----
    int4 h0 = ((int4*)hbase)[0];
    int4 h1 = ((int4*)hbase)[1];
    int4 h2 = ((int4*)hbase)[2];
    // Re-zero for the next grid-stride batch (in-order, before next adds).
    ((int4*)hbase)[0] = z;
    ((int4*)hbase)[1] = z;
    ((int4*)hbase)[2] = z;

    int hw[10] = {h0.x, h0.y, h0.z, h0.w, h1.x, h1.y, h1.z, h1.w, h2.x, h2.y};
    float s = 0.0f;
#pragma unroll
    for (int i = 0; i < 10; ++i) {
      unsigned w = (unsigned)hw[i];
#pragma unroll
      for (int b = 0; b < 4; ++b) {
        float c = (float)((w >> (8 * b)) & 0xFFu);
        float p = c * 0.015625f;             // counts / 64  (64+1e-8 == 64.0f)
        s += p * __logf(p + 1e-8f);          // c==0 contributes exactly 0
      }
    }

    out[(long)batch * 64 + l] = -s;          // coalesced 256 B per wave
  }
}

extern "C" void kernel_launch(void* const* d_in, const int* in_sizes, int n_in,
                              void* d_out, int out_size, void* d_ws, size_t ws_size,
                              hipStream_t stream) {
  const int* x = (const int*)d_in[0];
  float* out = (float*)d_out;

  const int n = in_sizes[0];        // B * 64 elements
  const int nbatch = n / 4096;      // 64-row batches (B = 262144 -> 4096)

  int blocks = (nbatch + WPB - 1) / WPB;  // one batch per wave (1024 blocks)
  if (blocks > 2048) blocks = 2048;       // safety: grid-stride covers rest
  if (blocks < 1) blocks = 1;

  entropy_rowlane_kernel<<<blocks, BLOCK, 0, stream>>>(x, out, nbatch);
}

// Round 4
// 90.968 us; speedup vs baseline: 1.0062x; 1.0062x over previous
//
#include <hip/hip_runtime.h>
#include <math.h>

// Batched histogram entropy: B rows x 64 int32 tokens, VOCAB=40.
// One lane = one row; coalesced int4 stage -> byte-packed LDS transpose ->
// per-lane byte-packed histogram via fire-and-forget ds_add_u32 -> VALU sweep.
//
// R4 = R3 with the nonexistent __builtin_amdgcn_cvt_f32_ubyteN replaced by
// (float)((w >> 8b) & 0xFF) — LLVM ISel pattern-matches this to
// v_cvt_f32_ubyte{0..3}, same codegen.
//
//  * HSTRIDE 13 (odd): stride-12 folded 64 lanes onto 8 LDS banks
//    (gcd(12,32)=4) => 8-way conflict (2.94x) on every hot-loop ds_add.
//    Odd stride spreads lanes over all 32 banks (2-way alias = free, m136).
//  * Sweep in log2 form: p*ln(p+eps) = ln2*(c/64)*(log2(c+64*eps)-6),
//    exact 0 for c==0, native v_log_f32.

#define NVOCAB 40

constexpr int BLOCK = 256;
constexpr int WPB = 4;           // waves per block
constexpr int TSTRIDE = 20;      // ints per packed tile row (16 used + 4 pad)
constexpr int HSTRIDE = 13;      // ints per lane histogram (10 used + 3 pad; ODD)

__global__ __launch_bounds__(BLOCK) void entropy_rowlane_kernel(
    const int* __restrict__ x, float* __restrict__ out, int nbatch) {
  __shared__ int tile[WPB * 64 * TSTRIDE];   // 20480 B
  __shared__ int hist[WPB * 64 * HSTRIDE];   // 13312 B

  const int tid = threadIdx.x;
  const int l   = tid & 63;
  const int wv  = tid >> 6;

  int* const tbase = &tile[wv * 64 * TSTRIDE];
  int* const hbase = &hist[(wv * 64 + l) * HSTRIDE];

  // Zero my histogram (DS ops are wave-in-order: done before any ds_add below).
#pragma unroll
  for (int i = 0; i < 10; ++i) hbase[i] = 0;

  const int4* const x4 = (const int4*)x;

  int batch = blockIdx.x * WPB + wv;
  const int batch_step = gridDim.x * WPB;

  for (; batch < nbatch; batch += batch_step) {
    const long base4 = (long)batch * 1024;  // int4 index of this 64-row batch

    // ---- stage: 16 coalesced 1 KiB loads, all in flight ----
    int4 va[8], vb[8];
#pragma unroll
    for (int t = 0; t < 8; ++t) va[t] = x4[base4 + t * 64 + l];
#pragma unroll
    for (int t = 0; t < 8; ++t) vb[t] = x4[base4 + (t + 8) * 64 + l];

    const int wrow = l >> 4;   // which of the 4 rows this lane's chunk feeds
    const int wcol = l & 15;   // packed-int column within the row
#pragma unroll
    for (int t = 0; t < 8; ++t) {
      int p = va[t].x | (va[t].y << 8) | (va[t].z << 16) | (va[t].w << 24);
      tbase[(4 * t + wrow) * TSTRIDE + wcol] = p;
    }
#pragma unroll
    for (int t = 0; t < 8; ++t) {
      int p = vb[t].x | (vb[t].y << 8) | (vb[t].z << 16) | (vb[t].w << 24);
      tbase[(4 * (t + 8) + wrow) * TSTRIDE + wcol] = p;
    }

    // Cross-lane LDS RAW: HW DS ops are wave-in-order; zero-cost scheduling
    // fence stops the compiler hoisting the reads above the writes.
    __builtin_amdgcn_wave_barrier();

    // ---- my packed row: 64 B = 4 x ds_read_b128 ----
    const int4* const rbase = (const int4*)(tbase + l * TSTRIDE);
    int4 r0 = rbase[0], r1 = rbase[1], r2 = rbase[2], r3 = rbase[3];
    int rw[16] = {r0.x, r0.y, r0.z, r0.w, r1.x, r1.y, r1.z, r1.w,
                  r2.x, r2.y, r2.z, r2.w, r3.x, r3.y, r3.z, r3.w};

    // ---- count: 64 fire-and-forget ds_add_u32, byte-packed bins ----
#pragma unroll
    for (int i = 0; i < 16; ++i) {
      unsigned w = (unsigned)rw[i];
#pragma unroll
      for (int b = 0; b < 4; ++b) {
        unsigned v = (w >> (8 * b)) & 0xFFu;
        atomicAdd((unsigned*)&hbase[v >> 2], 1u << ((v << 3) & 24u));
      }
    }

    __builtin_amdgcn_wave_barrier();

    // ---- sweep: 40 byte-counters -> entropy on the VALU ----
    int4 h0 = ((int4*)hbase)[0];
    int4 h1 = ((int4*)hbase)[1];
    int h8 = hbase[8], h9 = hbase[9];
    // Re-zero for the next grid-stride batch (in-order, before next adds).
#pragma unroll
    for (int i = 0; i < 10; ++i) hbase[i] = 0;

    int hw[10] = {h0.x, h0.y, h0.z, h0.w, h1.x, h1.y, h1.z, h1.w, h8, h9};
    float s = 0.0f;
#pragma unroll
    for (int i = 0; i < 10; ++i) {
      unsigned w = (unsigned)hw[i];
      // uitofp(byte extract) -> v_cvt_f32_ubyte{0..3} via ISel.
      float c0 = (float)(w & 0xFFu);
      float c1 = (float)((w >> 8) & 0xFFu);
      float c2 = (float)((w >> 16) & 0xFFu);
      float c3 = (float)((w >> 24) & 0xFFu);
      // c * (log2(c + 64*eps) - 6); exactly 0 for c == 0.
      s = __builtin_fmaf(c0, __log2f(c0 + 6.4e-7f) - 6.0f, s);
      s = __builtin_fmaf(c1, __log2f(c1 + 6.4e-7f) - 6.0f, s);
      s = __builtin_fmaf(c2, __log2f(c2 + 6.4e-7f) - 6.0f, s);
      s = __builtin_fmaf(c3, __log2f(c3 + 6.4e-7f) - 6.0f, s);
    }

    // -ln2/64: converts sum of c*log2 terms to -(1/64)*sum c*ln(...)
    out[(long)batch * 64 + l] = s * (-0.6931471805599453f * 0.015625f);
  }
}

extern "C" void kernel_launch(void* const* d_in, const int* in_sizes, int n_in,
                              void* d_out, int out_size, void* d_ws, size_t ws_size,
                              hipStream_t stream) {
  const int* x = (const int*)d_in[0];
  float* out = (float*)d_out;

  const int n = in_sizes[0];        // B * 64 elements
  const int nbatch = n / 4096;      // 64-row batches (B = 262144 -> 4096)

  int blocks = (nbatch + WPB - 1) / WPB;  // one batch per wave
  if (blocks > 2048) blocks = 2048;       // grid-stride covers any excess
  if (blocks < 1) blocks = 1;

  entropy_rowlane_kernel<<<blocks, BLOCK, 0, stream>>>(x, out, nbatch);
}